// Round 10
// baseline (112.169 us; speedup 1.0000x reference)
//
#include <hip/hip_runtime.h>

// 2-layer GRU, B=131072, T=24, H=8. MFMA formulation (round-8, verified) +
// round-9 scheduling: permlane32_swap instead of ds_bpermute, software
// pipeline (d1 carried one step ahead; dh issued at top of step; G1 row
// prefetched), G1 stride 26->33 (odd => conflict-free across tokens).

typedef __fp16 h2f    __attribute__((ext_vector_type(2)));
typedef __fp16 half8  __attribute__((ext_vector_type(8)));
typedef float  f32x16 __attribute__((ext_vector_type(16)));

#define LOG2E 1.44269504088896f

__device__ __forceinline__ h2f pk2f(float a, float b) {
  return __builtin_amdgcn_cvt_pkrtz(a, b);
}

union H8U { half8 h; unsigned u[4]; h2f p[4]; };

// lanes<32 receive x from lane+32; lanes>=32 get their own value (don't-care:
// A-frag rows k=8..15 are zero so the B content there never contributes).
__device__ __forceinline__ unsigned from_upper(unsigned x) {
  auto r = __builtin_amdgcn_permlane32_swap((int)x, (int)x, false, false);
  return (unsigned)r[1];
}

__global__ __launch_bounds__(256, 4) void gru2_mfma(
    const int* __restrict__ inputs,
    const float* __restrict__ emb,
    const float* __restrict__ w_ih1, const float* __restrict__ w_hh1,
    const float* __restrict__ b_ih1, const float* __restrict__ b_hh1,
    const float* __restrict__ w_ih2, const float* __restrict__ w_hh2,
    const float* __restrict__ b_ih2, const float* __restrict__ b_hh2,
    float* __restrict__ out)
{
  __shared__ float G1f[27 * 33];   // [token][gate], stride 33 (odd): token->bank bijective
  __shared__ int   TK[128 * 25];

  const int tid   = threadIdx.x;
  const int lane  = tid & 63;
  const int wid   = tid >> 6;
  const int half_ = lane >> 5;
  const int col   = lane & 31;

  // ---- G1 table: scaled input-side gates for all 27 tokens ----
  for (int idx = tid; idx < 27 * 24; idx += 256) {
    const int tok = idx / 24, g = idx - tok * 24;
    const float s = (g < 16) ? -LOG2E : 2.f * LOG2E;
    float a = b_ih1[g] + ((g < 16) ? b_hh1[g] : 0.f);
    if (tok != 0) {
      #pragma unroll
      for (int j = 0; j < 8; ++j) a = fmaf(w_ih1[g * 8 + j], emb[tok * 8 + j], a);
    }
    G1f[tok * 33 + g] = s * a;
  }

  // ---- stage tokens (coalesced) ----
  const long gbase = (long)blockIdx.x * (128 * 24);
  #pragma unroll
  for (int k = 0; k < 12; ++k) {
    const int i = tid + k * 256;
    TK[(i / 24) * 25 + (i % 24)] = inputs[gbase + i];
  }
  __syncthreads();

  const int sl = wid * 32 + col;
  unsigned pkw[4] = {0u, 0u, 0u, 0u};
  #pragma unroll
  for (int t = 0; t < 24; ++t)
    pkw[t / 6] |= ((unsigned)TK[sl * 25 + t]) << (5 * (t % 6));
  const unsigned pk0 = pkw[0], pk1 = pkw[1], pk2_ = pkw[2], pk3 = pkw[3];

  auto tok_at = [&](int t) -> unsigned {   // t compile-time under full unroll
    const unsigned pw = (t < 6) ? pk0 : (t < 12) ? pk1 : (t < 18) ? pk2_ : pk3;
    return (pw >> (5 * (t % 6))) & 31u;
  };

  // ---- weight A-frags (lane<32: row=col of W, k=0..7 scaled; else zero) ----
  auto loadW = [&](const float* w) -> half8 {
    H8U u;
    u.u[0] = u.u[1] = u.u[2] = u.u[3] = 0u;
    if (half_ == 0 && col < 24) {
      const float s = (col < 16) ? -LOG2E : 2.f * LOG2E;
      const float4* p = (const float4*)(w + col * 8);
      const float4 x = p[0], y = p[1];
      u.p[0] = pk2f(x.x * s, x.y * s);
      u.p[1] = pk2f(x.z * s, x.w * s);
      u.p[2] = pk2f(y.x * s, y.y * s);
      u.p[3] = pk2f(y.z * s, y.w * s);
    }
    return u.h;
  };
  const half8 wa1  = loadW(w_hh1);
  const half8 wa2i = loadW(w_ih2);
  const half8 wa2h = loadW(w_hh2);

  // ---- layer-2 bias C-frag ----
  f32x16 c2;
  #pragma unroll
  for (int r = 0; r < 16; ++r) {
    const int m = (r & 3) + 8 * (r >> 2) + 4 * half_;
    float v;
    if (m < 16)      v = -LOG2E * (b_ih2[m] + b_hh2[m]);
    else if (m < 24) v = 2.f * LOG2E * b_hh2[m];
    else             v = 0.f;
    c2[r] = v;
  }
  float bn1[4], bi2n[4];
  #pragma unroll
  for (int i = 0; i < 4; ++i) {
    bn1[i]  = 2.f * LOG2E * b_hh1[16 + 4 * half_ + i];
    bi2n[i] = 2.f * LOG2E * b_ih2[16 + 4 * half_ + i];
  }

  float h1v[4] = {0.f, 0.f, 0.f, 0.f}, h2v[4] = {0.f, 0.f, 0.f, 0.f};
  H8U f1, f2;
  f1.u[0] = f1.u[1] = f1.u[2] = f1.u[3] = 0u;
  f2 = f1;

  const float* g1base = G1f + half_ * 4;

  // ---- prologue: c1(0), gin1(0); d1(0) == c1(0) since f1 == 0 ----
  f32x16 c1;
  c1[8] = bn1[0]; c1[9] = bn1[1]; c1[10] = bn1[2]; c1[11] = bn1[3];
  c1[12] = 0.f; c1[13] = 0.f; c1[14] = 0.f; c1[15] = 0.f;
  float gin1[4];
  {
    const float* gp = g1base + tok_at(0) * 33;
    c1[0] = gp[0];  c1[1] = gp[1];  c1[2] = gp[2];  c1[3] = gp[3];
    c1[4] = gp[8];  c1[5] = gp[9];  c1[6] = gp[10]; c1[7] = gp[11];
    gin1[0] = gp[16]; gin1[1] = gp[17]; gin1[2] = gp[18]; gin1[3] = gp[19];
  }
  f32x16 d1 = c1;

  #pragma unroll
  for (int t = 0; t < 24; ++t) {
    // 1. prefetch next step's table row (independent; ds_read2_b32 pairs)
    float nc[8], ng[4];
    if (t < 23) {
      const float* gp = g1base + tok_at(t + 1) * 33;
      nc[0] = gp[0];  nc[1] = gp[1];  nc[2] = gp[2];  nc[3] = gp[3];
      nc[4] = gp[8];  nc[5] = gp[9];  nc[6] = gp[10]; nc[7] = gp[11];
      ng[0] = gp[16]; ng[1] = gp[17]; ng[2] = gp[18]; ng[3] = gp[19];
    }

    // 2. layer-2 recurrent mfma (f2 from prev step) — issued before L1 chain
    const f32x16 dh = __builtin_amdgcn_mfma_f32_32x32x16_f16(wa2h, f2.h, c2, 0, 0, 0);

    // 3. layer-1 cell from pipelined d1
    #pragma unroll
    for (int i = 0; i < 4; ++i) {
      const float r = __builtin_amdgcn_rcpf(1.f + __builtin_amdgcn_exp2f(d1[i]));
      const float z = __builtin_amdgcn_rcpf(1.f + __builtin_amdgcn_exp2f(d1[4 + i]));
      const float na = fmaf(r, d1[8 + i], gin1[i]);
      const float n = fmaf(-2.f, __builtin_amdgcn_rcpf(1.f + __builtin_amdgcn_exp2f(na)), 1.f);
      h1v[i] = n + z * (h1v[i] - n);
    }
    {
      const unsigned a = __builtin_bit_cast(unsigned, pk2f(h1v[0], h1v[1]));
      const unsigned b = __builtin_bit_cast(unsigned, pk2f(h1v[2], h1v[3]));
      f1.u[0] = a; f1.u[1] = b;
      f1.u[2] = from_upper(a); f1.u[3] = from_upper(b);
    }

    // 4. layer-2 input mfma chained on dh (needed immediately by L2 cell)
    const f32x16 dg = __builtin_amdgcn_mfma_f32_32x32x16_f16(wa2i, f1.h, dh, 0, 0, 0);

    // 5. commit next c1 and issue next-step layer-1 mfma (whole iteration of slack)
    if (t < 23) {
      c1[0] = nc[0]; c1[1] = nc[1]; c1[2] = nc[2]; c1[3] = nc[3];
      c1[4] = nc[4]; c1[5] = nc[5]; c1[6] = nc[6]; c1[7] = nc[7];
      gin1[0] = ng[0]; gin1[1] = ng[1]; gin1[2] = ng[2]; gin1[3] = ng[3];
      d1 = __builtin_amdgcn_mfma_f32_32x32x16_f16(wa1, f1.h, c1, 0, 0, 0);
    }

    // 6. layer-2 cell
    #pragma unroll
    for (int i = 0; i < 4; ++i) {
      const float r = __builtin_amdgcn_rcpf(1.f + __builtin_amdgcn_exp2f(dg[i]));
      const float z = __builtin_amdgcn_rcpf(1.f + __builtin_amdgcn_exp2f(dg[4 + i]));
      const float gin = dg[8 + i] - dh[8 + i] + bi2n[i];
      const float na = fmaf(r, dh[8 + i], gin);
      const float n = fmaf(-2.f, __builtin_amdgcn_rcpf(1.f + __builtin_amdgcn_exp2f(na)), 1.f);
      h2v[i] = n + z * (h2v[i] - n);
    }
    {
      const unsigned a = __builtin_bit_cast(unsigned, pk2f(h2v[0], h2v[1]));
      const unsigned b = __builtin_bit_cast(unsigned, pk2f(h2v[2], h2v[3]));
      f2.u[0] = a; f2.u[1] = b;
      f2.u[2] = from_upper(a); f2.u[3] = from_upper(b);
    }
  }

  const long seq = (long)blockIdx.x * 128 + sl;
  *(float4*)(out + seq * 8 + 4 * half_) =
      make_float4(h2v[0], h2v[1], h2v[2], h2v[3]);
}

extern "C" void kernel_launch(void* const* d_in, const int* in_sizes, int n_in,
                              void* d_out, int out_size, void* d_ws, size_t ws_size,
                              hipStream_t stream) {
  const int*   inputs = (const int*)d_in[0];
  const float* emb    = (const float*)d_in[1];
  const float* w_ih1  = (const float*)d_in[2];
  const float* w_hh1  = (const float*)d_in[3];
  const float* b_ih1  = (const float*)d_in[4];
  const float* b_hh1  = (const float*)d_in[5];
  const float* w_ih2  = (const float*)d_in[6];
  const float* w_hh2  = (const float*)d_in[7];
  const float* b_ih2  = (const float*)d_in[8];
  const float* b_hh2  = (const float*)d_in[9];
  float* out = (float*)d_out;

  const int B = in_sizes[0] / 24;        // 131072
  const int grid = B / 128;              // 1024 blocks

  hipLaunchKernelGGL(gru2_mfma, dim3(grid), dim3(256), 0, stream,
                     inputs, emb, w_ih1, w_hh1, b_ih1, b_hh1,
                     w_ih2, w_hh2, b_ih2, b_hh2, out);
}